// Round 12
// baseline (95.738 us; speedup 1.0000x reference)
//
#include <hip/hip_runtime.h>
#include <hip/hip_bf16.h>

// Interpolate1D: z = interp(cumsum(softmax(x@W + b)), y); outputs (z[B], x[B,64], logdet[B]+log|slope|)
// B=524288, D=64, R=256.
//
// Round-12: global-W (no LDS W copy) with a SANE register budget.
//   r9 already tried global-W but demanded 8 waves/EU -> allocator squeezed to 32 regs
//   -> scratch spill (FETCH 268MB/WRITE 238MB). The structure was fine; the demand was
//   the bug. Now: fused body + (256,4) budget (natural ~52-60 regs, r11-measured),
//   W pre-packed to d_ws in MFMA frag layout (32KB = exactly L1-size, L2-resident),
//   LDS = 2KB (bp+bias only) -> no 32KB-per-block LDS anchor, no per-block W pack,
//   no steady-state __syncthreads. 2048 blocks = 8 blocks/CU resident.
// Kept (verified across r4-r11): 16x16x32 MFMA swapped operands (W as A), register
// prefetch, LICM fence (32 loop-invariant W loads would hoist into 128 VGPRs),
// log2e pre-scale + __builtin_amdgcn_exp2f, float-mask prefix sums, branchless
// searchsorted, truncating bf16 x-pack (now 1-instr v_perm_b32).
// Assumes ws_size >= 33KB.

#define NB 524288
#define NWT (NB / 16)   // 32768 wave-tiles of 16 rows

typedef __attribute__((ext_vector_type(4))) float f32x4;
typedef __attribute__((ext_vector_type(4))) unsigned int u32x4;
typedef __attribute__((ext_vector_type(8))) __bf16 bf16x8;

#define LOG2E 1.4426950408889634f

static __device__ __forceinline__ unsigned short f2b(float f) {
    unsigned u = __builtin_bit_cast(unsigned, f);
    u += 0x7fffu + ((u >> 16) & 1u);          // RNE (W pack only; one-time)
    return (unsigned short)(u >> 16);
}
static __device__ __forceinline__ unsigned pk2t(float a, float b) {
    // truncating bf16x2 pack via byte-permute: {b.hi16, a.hi16} in one v_perm_b32
    return __builtin_amdgcn_perm(__builtin_bit_cast(unsigned, b),
                                 __builtin_bit_cast(unsigned, a), 0x07060302u);
}

// --- pack kernel: W*log2e -> bf16 MFMA-frag layout in d_ws; bias*log2e appended ---
__global__ __launch_bounds__(256) void pack_kernel(
    const float* __restrict__ W, const float* __restrict__ bias,
    unsigned short* __restrict__ wpack, float* __restrict__ bpack)
{
    const int k = blockIdx.x;       // 64 blocks: one W row each
    const int t = threadIdx.x;      // W column
    float wv = W[k * 256 + t] * LOG2E;
    int lane16 = ((k >> 3) & 3) * 16 + (t & 15);
    int n = t >> 4, kb = k >> 5, i = k & 7;
    wpack[((kb * 16 + n) * 64 + lane16) * 8 + i] = f2b(wv);
    if (k == 0) bpack[t] = bias[t] * LOG2E;
}

__global__ __launch_bounds__(256, 4) void interp1d_kernel(
    const float* __restrict__ y, const float* __restrict__ x,
    const unsigned short* __restrict__ wpack, const float* __restrict__ bpack,
    const float* __restrict__ logdet, const float* __restrict__ bp,
    float* __restrict__ out)
{
    __shared__ float sBP[256];
    __shared__ float sBias[256];    // 2KB total LDS

    const int t = threadIdx.x;
    sBP[t]   = bp[t];
    sBias[t] = bpack[t];
    __syncthreads();                // once; no steady-state barriers

    const int lane = t & 63;
    const int colb = lane & 15;     // this lane's x-row within the tile (C column)
    const int kH   = lane >> 4;     // 0..3: k-half for frags; C row group (cols kH*4+j)
    const int nw   = gridDim.x << 2;

    int wt = (blockIdx.x << 2) | (t >> 6);

    // --- preload first tile ---
    f32x4 v0 = {}, v1 = {}, v2 = {}, v3 = {};
    float yv = 0.f, ldv = 0.f;
    if (wt < NWT) {
        const float* xr = x + (size_t)((wt << 4) + colb) * 64 + (kH << 3);
        v0 = *reinterpret_cast<const f32x4*>(xr);
        v1 = *reinterpret_cast<const f32x4*>(xr + 4);
        v2 = *reinterpret_cast<const f32x4*>(xr + 32);
        v3 = *reinterpret_cast<const f32x4*>(xr + 36);
        yv  = y[(wt << 4) + colb];
        ldv = logdet[(wt << 4) + colb];
    }

    for (; wt < NWT; wt += nw) {
        const int m0 = wt << 4;
        const int wtn = wt + nw;

        // --- prefetch next tile (latency hidden under this tile's compute) ---
        f32x4 n0 = {}, n1 = {}, n2 = {}, n3 = {};
        float yn = 0.f, ldn = 0.f;
        if (wtn < NWT) {
            const float* xr = x + (size_t)((wtn << 4) + colb) * 64 + (kH << 3);
            n0 = *reinterpret_cast<const f32x4*>(xr);
            n1 = *reinterpret_cast<const f32x4*>(xr + 4);
            n2 = *reinterpret_cast<const f32x4*>(xr + 32);
            n3 = *reinterpret_cast<const f32x4*>(xr + 36);
            yn  = y[(wtn << 4) + colb];
            ldn = logdet[(wtn << 4) + colb];
        }

        // fence: keep the 32 loop-invariant wpack loads INSIDE the loop (r3 LICM lesson)
        asm volatile("" ::: "memory");

        // --- passthrough x store from the same registers ---
        float* xo = out + NB + (size_t)(m0 + colb) * 64 + (kH << 3);
        *reinterpret_cast<f32x4*>(xo)      = v0;
        *reinterpret_cast<f32x4*>(xo + 4)  = v1;
        *reinterpret_cast<f32x4*>(xo + 32) = v2;
        *reinterpret_cast<f32x4*>(xo + 36) = v3;

        // --- pack x into B-fragment (col = x-row = lane&15, k = kH*8+i) ---
        u32x4 pa, pb;
        pa[0] = pk2t(v0[0], v0[1]); pa[1] = pk2t(v0[2], v0[3]);
        pa[2] = pk2t(v1[0], v1[1]); pa[3] = pk2t(v1[2], v1[3]);
        pb[0] = pk2t(v2[0], v2[1]); pb[1] = pk2t(v2[2], v2[3]);
        pb[2] = pk2t(v3[0], v3[1]); pb[3] = pk2t(v3[2], v3[3]);
        bf16x8 a0 = __builtin_bit_cast(bf16x8, pa);
        bf16x8 a1 = __builtin_bit_cast(bf16x8, pb);

        // --- searchsorted (branchless: bp ~ linspace so guess is off by <= 1) ---
        int s = (int)floorf(yv * 255.0f);
        s = min(254, max(0, s));
        s += (sBP[s + 1] <= yv) ? 1 : 0;   // bp[255]=1.0 > yv, can't reach 255
        s = min(s, 254);
        s -= (sBP[s] > yv) ? 1 : 0;
        s = max(s, 0);

        // --- per-lane float masks for the partial blocks ---
        const int sb  = s >> 4,  so  = s & 15;            // block/offset of s
        const int sb1 = (s + 1) >> 4, so1 = (s + 1) & 15; // block/offset of s+1
        float m[4], pm[4];
        #pragma unroll
        for (int j = 0; j < 4; ++j) {
            m[j]  = ((kH << 2) + j <= so)  ? 1.f : 0.f;
            pm[j] = ((kH << 2) + j == so1) ? 1.f : 0.f;
        }

        // --- FUSED n-loop: W-frags from global (L1/L2-resident 32KB), MFMA (transient c),
        //     exp2, masked sums. No LDS, no AGPR array. ---
        float denom = 0.f, f0s = 0.f, p1 = 0.f;
        #pragma unroll
        for (int n = 0; n < 16; ++n) {
            bf16x8 w0 = *reinterpret_cast<const bf16x8*>(wpack + (n * 64 + lane) * 8);
            bf16x8 w1 = *reinterpret_cast<const bf16x8*>(wpack + ((16 + n) * 64 + lane) * 8);
            f32x4 c = *reinterpret_cast<const f32x4*>(&sBias[(n << 4) + (kH << 2)]);
            c = __builtin_amdgcn_mfma_f32_16x16x32_bf16(w0, a0, c, 0, 0, 0);
            c = __builtin_amdgcn_mfma_f32_16x16x32_bf16(w1, a1, c, 0, 0, 0);
            float e0 = __builtin_amdgcn_exp2f(c[0]);
            float e1 = __builtin_amdgcn_exp2f(c[1]);
            float e2 = __builtin_amdgcn_exp2f(c[2]);
            float e3 = __builtin_amdgcn_exp2f(c[3]);
            float bs = (e0 + e1) + (e2 + e3);
            denom += bs;
            float t0 = fmaf(e3, m[3], fmaf(e2, m[2], fmaf(e1, m[1], e0 * m[0])));
            float tp = fmaf(e3, pm[3], fmaf(e2, pm[2], fmaf(e1, pm[1], e0 * pm[0])));
            f0s += (n < sb) ? bs : ((n == sb) ? t0 : 0.f);
            p1  += (n == sb1) ? tp : 0.f;
        }

        // --- reduce over the 4 kH lanes sharing this x-row ---
        denom += __shfl_xor(denom, 16, 64);
        f0s   += __shfl_xor(f0s,   16, 64);
        p1    += __shfl_xor(p1,    16, 64);
        denom += __shfl_xor(denom, 32, 64);
        f0s   += __shfl_xor(f0s,   32, 64);
        p1    += __shfl_xor(p1,    32, 64);

        if (kH == 0) {   // lanes 0..15 store rows m0..m0+15: contiguous 64B
            float x0 = sBP[s], x1 = sBP[s + 1];
            float inv = 1.0f / denom;
            float f0 = f0s * inv;
            float slope = (p1 * inv) / (x1 - x0);
            out[m0 + colb] = fmaf(slope, yv - x0, f0);
            out[(size_t)NB * 65 + m0 + colb] = ldv + __logf(fabsf(slope));
        }

        // --- rotate prefetched tile in ---
        if (wtn < NWT) {
            v0 = n0; v1 = n1; v2 = n2; v3 = n3;
            yv = yn; ldv = ldn;
        }
    }
}

extern "C" void kernel_launch(void* const* d_in, const int* in_sizes, int n_in,
                              void* d_out, int out_size, void* d_ws, size_t ws_size,
                              hipStream_t stream) {
    (void)in_sizes; (void)n_in; (void)out_size; (void)ws_size;
    const float* y      = (const float*)d_in[0];
    const float* x      = (const float*)d_in[1];
    const float* W      = (const float*)d_in[2];
    const float* b      = (const float*)d_in[3];
    const float* logdet = (const float*)d_in[4];
    const float* bp     = (const float*)d_in[5];
    float* out = (float*)d_out;

    unsigned short* wpack = (unsigned short*)d_ws;            // 32KB frag-layout bf16 W
    float* bpack = (float*)((char*)d_ws + 32768);             // 1KB bias*log2e

    pack_kernel<<<dim3(64), dim3(256), 0, stream>>>(W, b, wpack, bpack);
    // 2048 blocks x 256 thr = 8 blocks/CU (thread-capped; LDS 2KB, regs <=64 natural)
    // -> up to 32 waves/CU. 4 tiles/wave.
    interp1d_kernel<<<dim3(2048), dim3(256), 0, stream>>>(y, x, wpack, bpack, logdet, bp, out);
}

// Round 13
// 87.018 us; speedup vs baseline: 1.1002x; 1.1002x over previous
//
#include <hip/hip_runtime.h>
#include <hip/hip_bf16.h>

// Interpolate1D: z = interp(cumsum(softmax(x@W + b)), y); outputs (z[B], x[B,64], logdet[B]+log|slope|)
// B=524288, D=64, R=256.
//
// Round-13 = round-11 (best: 64.2us) + HALF OF W HELD IN REGISTERS:
//   Pipe budget at r11: LDS ~26us (48 ds_read_b128/tile), HBM ~33us, VALU ~35us —
//   three co-equal pipes, imperfectly overlapped at ~4 waves/SIMD -> 64us.
//   r12 proved occupancy can't rise (36-40% plateau across 3 configs) and W can't
//   live in global (latency: 96us). So cut the LDS pipe: frags for n=0..7 (both
//   k-halves, 64 VGPRs) loaded once pre-loop with compile-time indices; n=8..15
//   still ds_read inside the fenced loop. 48 -> 32 b128/tile. Budget 52+64=116<=128
//   at (512,4) — same 4 waves/SIMD we measure anyway.
// Kept: 512-thr blocks (8 waves share sW), fused n-loop (transient acc), swapped
// MFMA operands, register prefetch, LICM fence, log2e pre-scale + exp2, float-mask
// prefix sums, branchless searchsorted, v_perm bf16x2 pack (r12-verified).

#define NB 524288
#define NWT (NB / 16)   // 32768 wave-tiles of 16 rows

typedef __attribute__((ext_vector_type(4))) float f32x4;
typedef __attribute__((ext_vector_type(4))) unsigned int u32x4;
typedef __attribute__((ext_vector_type(8))) __bf16 bf16x8;

#define LOG2E 1.4426950408889634f

static __device__ __forceinline__ unsigned short f2b(float f) {
    unsigned u = __builtin_bit_cast(unsigned, f);
    u += 0x7fffu + ((u >> 16) & 1u);          // RNE (W pack only; one-time)
    return (unsigned short)(u >> 16);
}
static __device__ __forceinline__ unsigned pk2t(float a, float b) {
    // truncating bf16x2 pack via byte-permute: {b.hi16 : a.hi16} in one v_perm_b32
    return __builtin_amdgcn_perm(__builtin_bit_cast(unsigned, b),
                                 __builtin_bit_cast(unsigned, a), 0x07060302u);
}

__global__ __launch_bounds__(512, 4) void interp1d_kernel(
    const float* __restrict__ y, const float* __restrict__ x,
    const float* __restrict__ W, const float* __restrict__ bias,
    const float* __restrict__ logdet, const float* __restrict__ bp,
    float* __restrict__ out)
{
    __shared__ unsigned short sW[2 * 16 * 64 * 8];   // 32KB, [kb][n][lane][i] frag layout
    __shared__ float sBP[256];
    __shared__ float sBias[256];                     // pre-scaled by log2e

    const int t = threadIdx.x;

    // --- once per block: bp, bias*log2e, W*log2e packed into MFMA fragment layout ---
    if (t < 256) {
        sBP[t]   = bp[t];
        sBias[t] = bias[t] * LOG2E;
    }
    {
        const int col = t & 255;
        const int k0  = (t >> 8) << 5;
        const int lane16lo = col & 15;
        const int n = col >> 4;
        for (int kk = 0; kk < 32; ++kk) {
            int k = k0 + kk;
            float wv = W[k * 256 + col] * LOG2E;      // coalesced within each 256-thread half
            int lane16 = ((k >> 3) & 3) * 16 + lane16lo;
            int kb = k >> 5, i = k & 7;
            sW[((kb * 16 + n) * 64 + lane16) * 8 + i] = f2b(wv);
        }
    }
    __syncthreads();

    const int lane = t & 63;
    const int colb = lane & 15;     // this lane's x-row within the tile (C column)
    const int kH   = lane >> 4;     // 0..3: k-half for frags; C row group (cols kH*4+j)
    const int nw   = gridDim.x << 3;            // 8 waves per block

    // --- hold W-frags for n=0..7 in registers (64 VGPRs, compile-time indexed) ---
    bf16x8 rw0[8], rw1[8];
    #pragma unroll
    for (int n = 0; n < 8; ++n) {
        rw0[n] = *reinterpret_cast<const bf16x8*>(&sW[(n * 64 + lane) * 8]);
        rw1[n] = *reinterpret_cast<const bf16x8*>(&sW[((16 + n) * 64 + lane) * 8]);
    }

    int wt = (blockIdx.x << 3) | (t >> 6);

    // --- preload first tile ---
    f32x4 v0 = {}, v1 = {}, v2 = {}, v3 = {};
    float yv = 0.f, ldv = 0.f;
    if (wt < NWT) {
        const float* xr = x + (size_t)((wt << 4) + colb) * 64 + (kH << 3);
        v0 = *reinterpret_cast<const f32x4*>(xr);
        v1 = *reinterpret_cast<const f32x4*>(xr + 4);
        v2 = *reinterpret_cast<const f32x4*>(xr + 32);
        v3 = *reinterpret_cast<const f32x4*>(xr + 36);
        yv  = y[(wt << 4) + colb];
        ldv = logdet[(wt << 4) + colb];
    }

    for (; wt < NWT; wt += nw) {
        const int m0 = wt << 4;
        const int wtn = wt + nw;

        // --- prefetch next tile (latency hidden under this tile's compute) ---
        f32x4 n0 = {}, n1 = {}, n2 = {}, n3 = {};
        float yn = 0.f, ldn = 0.f;
        if (wtn < NWT) {
            const float* xr = x + (size_t)((wtn << 4) + colb) * 64 + (kH << 3);
            n0 = *reinterpret_cast<const f32x4*>(xr);
            n1 = *reinterpret_cast<const f32x4*>(xr + 4);
            n2 = *reinterpret_cast<const f32x4*>(xr + 32);
            n3 = *reinterpret_cast<const f32x4*>(xr + 36);
            yn  = y[(wtn << 4) + colb];
            ldn = logdet[(wtn << 4) + colb];
        }

        // compiler fence: keep the n>=8 sW ds_reads inside the tile loop (r3 lesson);
        // rw0/rw1 were loaded into SSA values pre-loop and are unaffected.
        asm volatile("" ::: "memory");

        // --- passthrough x store from the same registers ---
        float* xo = out + NB + (size_t)(m0 + colb) * 64 + (kH << 3);
        *reinterpret_cast<f32x4*>(xo)      = v0;
        *reinterpret_cast<f32x4*>(xo + 4)  = v1;
        *reinterpret_cast<f32x4*>(xo + 32) = v2;
        *reinterpret_cast<f32x4*>(xo + 36) = v3;

        // --- pack x into B-fragment (col = x-row = lane&15, k = kH*8+i) ---
        u32x4 pa, pb;
        pa[0] = pk2t(v0[0], v0[1]); pa[1] = pk2t(v0[2], v0[3]);
        pa[2] = pk2t(v1[0], v1[1]); pa[3] = pk2t(v1[2], v1[3]);
        pb[0] = pk2t(v2[0], v2[1]); pb[1] = pk2t(v2[2], v2[3]);
        pb[2] = pk2t(v3[0], v3[1]); pb[3] = pk2t(v3[2], v3[3]);
        bf16x8 a0 = __builtin_bit_cast(bf16x8, pa);
        bf16x8 a1 = __builtin_bit_cast(bf16x8, pb);

        // --- searchsorted (branchless: bp ~ linspace so guess is off by <= 1) ---
        int s = (int)floorf(yv * 255.0f);
        s = min(254, max(0, s));
        s += (sBP[s + 1] <= yv) ? 1 : 0;   // bp[255]=1.0 > yv, can't reach 255
        s = min(s, 254);
        s -= (sBP[s] > yv) ? 1 : 0;
        s = max(s, 0);

        // --- per-lane float masks for the partial blocks ---
        const int sb  = s >> 4,  so  = s & 15;            // block/offset of s
        const int sb1 = (s + 1) >> 4, so1 = (s + 1) & 15; // block/offset of s+1
        float m[4], pm[4];
        #pragma unroll
        for (int j = 0; j < 4; ++j) {
            m[j]  = ((kH << 2) + j <= so)  ? 1.f : 0.f;
            pm[j] = ((kH << 2) + j == so1) ? 1.f : 0.f;
        }

        // --- FUSED n-loop: n<8 uses register-held W, n>=8 reads LDS ---
        float denom = 0.f, f0s = 0.f, p1 = 0.f;
        #pragma unroll
        for (int n = 0; n < 16; ++n) {
            bf16x8 w0, w1;
            if (n < 8) {
                w0 = rw0[n];
                w1 = rw1[n];
            } else {
                w0 = *reinterpret_cast<const bf16x8*>(&sW[(n * 64 + lane) * 8]);
                w1 = *reinterpret_cast<const bf16x8*>(&sW[((16 + n) * 64 + lane) * 8]);
            }
            f32x4 c = *reinterpret_cast<const f32x4*>(&sBias[(n << 4) + (kH << 2)]);
            c = __builtin_amdgcn_mfma_f32_16x16x32_bf16(w0, a0, c, 0, 0, 0);
            c = __builtin_amdgcn_mfma_f32_16x16x32_bf16(w1, a1, c, 0, 0, 0);
            float e0 = __builtin_amdgcn_exp2f(c[0]);
            float e1 = __builtin_amdgcn_exp2f(c[1]);
            float e2 = __builtin_amdgcn_exp2f(c[2]);
            float e3 = __builtin_amdgcn_exp2f(c[3]);
            float bs = (e0 + e1) + (e2 + e3);
            denom += bs;
            float t0 = fmaf(e3, m[3], fmaf(e2, m[2], fmaf(e1, m[1], e0 * m[0])));
            float tp = fmaf(e3, pm[3], fmaf(e2, pm[2], fmaf(e1, pm[1], e0 * pm[0])));
            f0s += (n < sb) ? bs : ((n == sb) ? t0 : 0.f);
            p1  += (n == sb1) ? tp : 0.f;
        }

        // --- reduce over the 4 kH lanes sharing this x-row ---
        denom += __shfl_xor(denom, 16, 64);
        f0s   += __shfl_xor(f0s,   16, 64);
        p1    += __shfl_xor(p1,    16, 64);
        denom += __shfl_xor(denom, 32, 64);
        f0s   += __shfl_xor(f0s,   32, 64);
        p1    += __shfl_xor(p1,    32, 64);

        if (kH == 0) {   // lanes 0..15 store rows m0..m0+15: contiguous 64B
            float x0 = sBP[s], x1 = sBP[s + 1];
            float inv = 1.0f / denom;
            float f0 = f0s * inv;
            float slope = (p1 * inv) / (x1 - x0);
            out[m0 + colb] = fmaf(slope, yv - x0, f0);
            out[(size_t)NB * 65 + m0 + colb] = ldv + __logf(fabsf(slope));
        }

        // --- rotate prefetched tile in ---
        if (wtn < NWT) {
            v0 = n0; v1 = n1; v2 = n2; v3 = n3;
            yv = yn; ldv = ldn;
        }
    }
}

extern "C" void kernel_launch(void* const* d_in, const int* in_sizes, int n_in,
                              void* d_out, int out_size, void* d_ws, size_t ws_size,
                              hipStream_t stream) {
    (void)in_sizes; (void)n_in; (void)out_size; (void)d_ws; (void)ws_size;
    const float* y      = (const float*)d_in[0];
    const float* x      = (const float*)d_in[1];
    const float* W      = (const float*)d_in[2];
    const float* b      = (const float*)d_in[3];
    const float* logdet = (const float*)d_in[4];
    const float* bp     = (const float*)d_in[5];
    float* out = (float*)d_out;
    // 512-thr blocks (8 waves share one 32KB sW); 1024 blocks = 4/CU resident; 4 tiles/wave.
    interp1d_kernel<<<dim3(1024), dim3(512), 0, stream>>>(y, x, W, b, logdet, bp, out);
}

// Round 14
// 67.397 us; speedup vs baseline: 1.4205x; 1.2911x over previous
//
#include <hip/hip_runtime.h>
#include <hip/hip_bf16.h>

// Interpolate1D: z = interp(cumsum(softmax(x@W + b)), y); outputs (z[B], x[B,64], logdet[B]+log|slope|)
// B=524288, D=64, R=256.
//
// Round-14 = r11 base + TILE-PAIRING: each wave processes 2 independent 16-row tiles
// per fused n-loop iteration, sharing every w0/w1/bias LDS read between the pair
// (LDS pipe halves: 3 b128 / 2 tiles) and giving the scheduler two independent
// MFMA->exp chains (the ILP the compiler refuses to create within one tile).
//   Register plan (r13 lesson: (*,4) caps arch-VGPR at 64 -> spill): (512,2) budget;
//   stage1 (store+pack+search+masks) compacts each tile to ~40 regs of state before
//   the next pair's x loads are issued. 8192 waves x 4 tiles == 32768 exactly.
// Kept: 512-thr blocks sharing one 32KB sW, swapped MFMA operands, LICM fences,
// log2e pre-scale + exp2, float-mask prefix sums, branchless searchsorted,
// v_perm bf16x2 pack.

#define NB 524288
#define NWT (NB / 16)       // 32768 tiles of 16 rows
#define NWAVES 8192         // 1024 blocks x 8 waves

typedef __attribute__((ext_vector_type(4))) float f32x4;
typedef __attribute__((ext_vector_type(4))) unsigned int u32x4;
typedef __attribute__((ext_vector_type(8))) __bf16 bf16x8;

#define LOG2E 1.4426950408889634f

static __device__ __forceinline__ unsigned short f2b(float f) {
    unsigned u = __builtin_bit_cast(unsigned, f);
    u += 0x7fffu + ((u >> 16) & 1u);          // RNE (W pack only; one-time)
    return (unsigned short)(u >> 16);
}
static __device__ __forceinline__ unsigned pk2t(float a, float b) {
    // truncating bf16x2 pack via byte-permute (r12-verified)
    return __builtin_amdgcn_perm(__builtin_bit_cast(unsigned, b),
                                 __builtin_bit_cast(unsigned, a), 0x07060302u);
}

struct TState {
    bf16x8 a0, a1;      // packed x fragments
    float yv, ldv;
    float m[4], pm[4];  // per-lane masks for boundary blocks (statically indexed)
    int s;
    int m0;
};

// stage1: passthrough store + bf16 pack + searchsorted + masks -> compact state
static __device__ __forceinline__ TState stage1(
    int wt, f32x4 v0, f32x4 v1, f32x4 v2, f32x4 v3, float yv, float ldv,
    int colb, int kH, const float* sBP, float* out)
{
    TState st;
    st.m0 = wt << 4; st.yv = yv; st.ldv = ldv;

    float* xo = out + NB + (size_t)(st.m0 + colb) * 64 + (kH << 3);
    *reinterpret_cast<f32x4*>(xo)      = v0;
    *reinterpret_cast<f32x4*>(xo + 4)  = v1;
    *reinterpret_cast<f32x4*>(xo + 32) = v2;
    *reinterpret_cast<f32x4*>(xo + 36) = v3;

    u32x4 pa, pb;
    pa[0] = pk2t(v0[0], v0[1]); pa[1] = pk2t(v0[2], v0[3]);
    pa[2] = pk2t(v1[0], v1[1]); pa[3] = pk2t(v1[2], v1[3]);
    pb[0] = pk2t(v2[0], v2[1]); pb[1] = pk2t(v2[2], v2[3]);
    pb[2] = pk2t(v3[0], v3[1]); pb[3] = pk2t(v3[2], v3[3]);
    st.a0 = __builtin_bit_cast(bf16x8, pa);
    st.a1 = __builtin_bit_cast(bf16x8, pb);

    int s = (int)floorf(yv * 255.0f);
    s = min(254, max(0, s));
    s += (sBP[s + 1] <= yv) ? 1 : 0;
    s = min(s, 254);
    s -= (sBP[s] > yv) ? 1 : 0;
    s = max(s, 0);
    st.s = s;

    const int so  = s & 15;
    const int so1 = (s + 1) & 15;
    #pragma unroll
    for (int j = 0; j < 4; ++j) {
        st.m[j]  = ((kH << 2) + j <= so)  ? 1.f : 0.f;
        st.pm[j] = ((kH << 2) + j == so1) ? 1.f : 0.f;
    }
    return st;
}

// stage2: shared-W fused n-loop for a PAIR of tiles + reduce + final stores
static __device__ __forceinline__ void stage2_pair(
    const TState& A, const TState& B, int lane, int colb, int kH,
    const unsigned short* sW, const float* sBP, const float* sBias, float* out)
{
    const int sbA = A.s >> 4, sbA1 = (A.s + 1) >> 4;
    const int sbB = B.s >> 4, sbB1 = (B.s + 1) >> 4;

    float dA = 0.f, fA = 0.f, pA = 0.f;
    float dB = 0.f, fB = 0.f, pB = 0.f;
    #pragma unroll
    for (int n = 0; n < 16; ++n) {
        bf16x8 w0 = *reinterpret_cast<const bf16x8*>(&sW[(n * 64 + lane) * 8]);
        bf16x8 w1 = *reinterpret_cast<const bf16x8*>(&sW[((16 + n) * 64 + lane) * 8]);
        f32x4 bi = *reinterpret_cast<const f32x4*>(&sBias[(n << 4) + (kH << 2)]);

        f32x4 cA = __builtin_amdgcn_mfma_f32_16x16x32_bf16(w0, A.a0, bi, 0, 0, 0);
        cA = __builtin_amdgcn_mfma_f32_16x16x32_bf16(w1, A.a1, cA, 0, 0, 0);
        f32x4 cB = __builtin_amdgcn_mfma_f32_16x16x32_bf16(w0, B.a0, bi, 0, 0, 0);
        cB = __builtin_amdgcn_mfma_f32_16x16x32_bf16(w1, B.a1, cB, 0, 0, 0);

        {   // tile A epilogue slice
            float e0 = __builtin_amdgcn_exp2f(cA[0]);
            float e1 = __builtin_amdgcn_exp2f(cA[1]);
            float e2 = __builtin_amdgcn_exp2f(cA[2]);
            float e3 = __builtin_amdgcn_exp2f(cA[3]);
            float bs = (e0 + e1) + (e2 + e3);
            dA += bs;
            float t0 = fmaf(e3, A.m[3], fmaf(e2, A.m[2], fmaf(e1, A.m[1], e0 * A.m[0])));
            float tp = fmaf(e3, A.pm[3], fmaf(e2, A.pm[2], fmaf(e1, A.pm[1], e0 * A.pm[0])));
            fA += (n < sbA) ? bs : ((n == sbA) ? t0 : 0.f);
            pA += (n == sbA1) ? tp : 0.f;
        }
        {   // tile B epilogue slice (independent chain)
            float e0 = __builtin_amdgcn_exp2f(cB[0]);
            float e1 = __builtin_amdgcn_exp2f(cB[1]);
            float e2 = __builtin_amdgcn_exp2f(cB[2]);
            float e3 = __builtin_amdgcn_exp2f(cB[3]);
            float bs = (e0 + e1) + (e2 + e3);
            dB += bs;
            float t0 = fmaf(e3, B.m[3], fmaf(e2, B.m[2], fmaf(e1, B.m[1], e0 * B.m[0])));
            float tp = fmaf(e3, B.pm[3], fmaf(e2, B.pm[2], fmaf(e1, B.pm[1], e0 * B.pm[0])));
            fB += (n < sbB) ? bs : ((n == sbB) ? t0 : 0.f);
            pB += (n == sbB1) ? tp : 0.f;
        }
    }

    dA += __shfl_xor(dA, 16, 64); fA += __shfl_xor(fA, 16, 64); pA += __shfl_xor(pA, 16, 64);
    dA += __shfl_xor(dA, 32, 64); fA += __shfl_xor(fA, 32, 64); pA += __shfl_xor(pA, 32, 64);
    dB += __shfl_xor(dB, 16, 64); fB += __shfl_xor(fB, 16, 64); pB += __shfl_xor(pB, 16, 64);
    dB += __shfl_xor(dB, 32, 64); fB += __shfl_xor(fB, 32, 64); pB += __shfl_xor(pB, 32, 64);

    if (kH == 0) {
        {
            float x0 = sBP[A.s], x1 = sBP[A.s + 1];
            float inv = 1.0f / dA;
            float slope = (pA * inv) / (x1 - x0);
            out[A.m0 + colb] = fmaf(slope, A.yv - x0, fA * inv);
            out[(size_t)NB * 65 + A.m0 + colb] = A.ldv + __logf(fabsf(slope));
        }
        {
            float x0 = sBP[B.s], x1 = sBP[B.s + 1];
            float inv = 1.0f / dB;
            float slope = (pB * inv) / (x1 - x0);
            out[B.m0 + colb] = fmaf(slope, B.yv - x0, fB * inv);
            out[(size_t)NB * 65 + B.m0 + colb] = B.ldv + __logf(fabsf(slope));
        }
    }
}

#define LOADT(wt, v0, v1, v2, v3, yv, ldv)                                     \
    {                                                                          \
        const float* xr = x + (size_t)(((wt) << 4) + colb) * 64 + (kH << 3);   \
        v0 = *reinterpret_cast<const f32x4*>(xr);                              \
        v1 = *reinterpret_cast<const f32x4*>(xr + 4);                          \
        v2 = *reinterpret_cast<const f32x4*>(xr + 32);                         \
        v3 = *reinterpret_cast<const f32x4*>(xr + 36);                         \
        yv  = y[((wt) << 4) + colb];                                           \
        ldv = logdet[((wt) << 4) + colb];                                      \
    }

__global__ __launch_bounds__(512, 2) void interp1d_kernel(
    const float* __restrict__ y, const float* __restrict__ x,
    const float* __restrict__ W, const float* __restrict__ bias,
    const float* __restrict__ logdet, const float* __restrict__ bp,
    float* __restrict__ out)
{
    __shared__ unsigned short sW[2 * 16 * 64 * 8];   // 32KB frag layout
    __shared__ float sBP[256];
    __shared__ float sBias[256];

    const int t = threadIdx.x;
    const int lane = t & 63;
    const int colb = lane & 15;
    const int kH   = lane >> 4;
    const int wid  = (blockIdx.x << 3) | (t >> 6);   // 0..8191

    // --- issue pair-1 x loads FIRST (overlap with W pack) ---
    f32x4 A0, A1, A2, A3, B0, B1, B2, B3;
    float yA, lA, yB, lB;
    LOADT(wid,          A0, A1, A2, A3, yA, lA);
    LOADT(wid + NWAVES, B0, B1, B2, B3, yB, lB);

    // --- once per block: bp, bias*log2e, W*log2e packed into frag layout ---
    if (t < 256) {
        sBP[t]   = bp[t];
        sBias[t] = bias[t] * LOG2E;
    }
    {
        const int col = t & 255;
        const int k0  = (t >> 8) << 5;
        const int lane16lo = col & 15;
        const int n = col >> 4;
        for (int kk = 0; kk < 32; ++kk) {
            int k = k0 + kk;
            float wv = W[k * 256 + col] * LOG2E;
            int lane16 = ((k >> 3) & 3) * 16 + lane16lo;
            int kb = k >> 5, i = k & 7;
            sW[((kb * 16 + n) * 64 + lane16) * 8 + i] = f2b(wv);
        }
    }
    __syncthreads();

    // --- pair 1: compact to state (frees raw x regs), then prefetch pair 2 ---
    TState sA = stage1(wid,          A0, A1, A2, A3, yA, lA, colb, kH, sBP, out);
    TState sB = stage1(wid + NWAVES, B0, B1, B2, B3, yB, lB, colb, kH, sBP, out);

    f32x4 C0, C1, C2, C3, D0, D1, D2, D3;
    float yC, lC, yD, lD;
    LOADT(wid + 2 * NWAVES, C0, C1, C2, C3, yC, lC);
    LOADT(wid + 3 * NWAVES, D0, D1, D2, D3, yD, lD);

    asm volatile("" ::: "memory");   // keep prefetch issued; no sW CSE across stages
    stage2_pair(sA, sB, lane, colb, kH, sW, sBP, sBias, out);

    asm volatile("" ::: "memory");   // block W ds_read CSE between the two pairs

    // --- pair 2 ---
    TState sC = stage1(wid + 2 * NWAVES, C0, C1, C2, C3, yC, lC, colb, kH, sBP, out);
    TState sD = stage1(wid + 3 * NWAVES, D0, D1, D2, D3, yD, lD, colb, kH, sBP, out);
    stage2_pair(sC, sD, lane, colb, kH, sW, sBP, sBias, out);
}

extern "C" void kernel_launch(void* const* d_in, const int* in_sizes, int n_in,
                              void* d_out, int out_size, void* d_ws, size_t ws_size,
                              hipStream_t stream) {
    (void)in_sizes; (void)n_in; (void)out_size; (void)d_ws; (void)ws_size;
    const float* y      = (const float*)d_in[0];
    const float* x      = (const float*)d_in[1];
    const float* W      = (const float*)d_in[2];
    const float* b      = (const float*)d_in[3];
    const float* logdet = (const float*)d_in[4];
    const float* bp     = (const float*)d_in[5];
    float* out = (float*)d_out;
    // 1024 blocks x 512 thr = 8192 waves; each processes exactly 2 pairs (4 tiles).
    interp1d_kernel<<<dim3(1024), dim3(512), 0, stream>>>(y, x, W, b, logdet, bp, out);
}

// Round 15
// 64.899 us; speedup vs baseline: 1.4752x; 1.0385x over previous
//
#include <hip/hip_runtime.h>
#include <hip/hip_bf16.h>

// Interpolate1D: z = interp(cumsum(softmax(x@W + b)), y); outputs (z[B], x[B,64], logdet[B]+log|slope|)
// B=524288, D=64, R=256.
//
// Round-15 = tile-PAIRING (r14's verified stage1/stage2_pair) put back into r11's
// grid-stride + prefetch structure:
//   Pipe model (corrected): LDS is a per-CU pipe: 48 b128/tile x 12cyc x 128 tiles/CU
//   ~= 31us ~ HBM 33us; VALU only ~15us. Pairing shares w0/w1/bias reads across 2
//   tiles -> 24 b128/tile -> LDS ~15us, leaving HBM as the single dominant pipe.
//   r14's one-shot wrapper (no loop, 22% occupancy) is replaced by: grid-stride over
//   pairs, prefetch next pair AFTER stage1 frees current x regs (live ranges don't
//   stack: ~106 regs <= 128 -> 4 waves/SIMD), (512,2) budget (r14: 72 regs, no spill),
//   512 blocks = 2 resident blocks/CU, 4 pair-iters/wave, W-pack amortized over 32 tiles.
// Kept verbatim (r14-validated numerics): stage1/stage2_pair, swapped MFMA operands,
// log2e pre-scale + exp2, float-mask prefix sums, branchless searchsorted, v_perm pack.

#define NB 524288
#define NWT (NB / 16)       // 32768 tiles of 16 rows
#define NPAIRS 16384
#define NWAVES 4096         // 512 blocks x 8 waves; 4 pair-iterations each

typedef __attribute__((ext_vector_type(4))) float f32x4;
typedef __attribute__((ext_vector_type(4))) unsigned int u32x4;
typedef __attribute__((ext_vector_type(8))) __bf16 bf16x8;

#define LOG2E 1.4426950408889634f

static __device__ __forceinline__ unsigned short f2b(float f) {
    unsigned u = __builtin_bit_cast(unsigned, f);
    u += 0x7fffu + ((u >> 16) & 1u);          // RNE (W pack only; one-time)
    return (unsigned short)(u >> 16);
}
static __device__ __forceinline__ unsigned pk2t(float a, float b) {
    // truncating bf16x2 pack via byte-permute (r12-verified)
    return __builtin_amdgcn_perm(__builtin_bit_cast(unsigned, b),
                                 __builtin_bit_cast(unsigned, a), 0x07060302u);
}

struct TState {
    bf16x8 a0, a1;      // packed x fragments
    float yv, ldv;
    float m[4], pm[4];  // per-lane masks (statically indexed)
    int s;
    int m0;
};

// stage1: passthrough store + bf16 pack + searchsorted + masks -> compact state
static __device__ __forceinline__ TState stage1(
    int wt, f32x4 v0, f32x4 v1, f32x4 v2, f32x4 v3, float yv, float ldv,
    int colb, int kH, const float* sBP, float* out)
{
    TState st;
    st.m0 = wt << 4; st.yv = yv; st.ldv = ldv;

    float* xo = out + NB + (size_t)(st.m0 + colb) * 64 + (kH << 3);
    *reinterpret_cast<f32x4*>(xo)      = v0;
    *reinterpret_cast<f32x4*>(xo + 4)  = v1;
    *reinterpret_cast<f32x4*>(xo + 32) = v2;
    *reinterpret_cast<f32x4*>(xo + 36) = v3;

    u32x4 pa, pb;
    pa[0] = pk2t(v0[0], v0[1]); pa[1] = pk2t(v0[2], v0[3]);
    pa[2] = pk2t(v1[0], v1[1]); pa[3] = pk2t(v1[2], v1[3]);
    pb[0] = pk2t(v2[0], v2[1]); pb[1] = pk2t(v2[2], v2[3]);
    pb[2] = pk2t(v3[0], v3[1]); pb[3] = pk2t(v3[2], v3[3]);
    st.a0 = __builtin_bit_cast(bf16x8, pa);
    st.a1 = __builtin_bit_cast(bf16x8, pb);

    int s = (int)floorf(yv * 255.0f);
    s = min(254, max(0, s));
    s += (sBP[s + 1] <= yv) ? 1 : 0;
    s = min(s, 254);
    s -= (sBP[s] > yv) ? 1 : 0;
    s = max(s, 0);
    st.s = s;

    const int so  = s & 15;
    const int so1 = (s + 1) & 15;
    #pragma unroll
    for (int j = 0; j < 4; ++j) {
        st.m[j]  = ((kH << 2) + j <= so)  ? 1.f : 0.f;
        st.pm[j] = ((kH << 2) + j == so1) ? 1.f : 0.f;
    }
    return st;
}

// stage2: shared-W fused n-loop for a PAIR of tiles + reduce + final stores
static __device__ __forceinline__ void stage2_pair(
    const TState& A, const TState& B, int lane, int colb, int kH,
    const unsigned short* sW, const float* sBP, const float* sBias, float* out)
{
    const int sbA = A.s >> 4, sbA1 = (A.s + 1) >> 4;
    const int sbB = B.s >> 4, sbB1 = (B.s + 1) >> 4;

    float dA = 0.f, fA = 0.f, pA = 0.f;
    float dB = 0.f, fB = 0.f, pB = 0.f;
    #pragma unroll
    for (int n = 0; n < 16; ++n) {
        bf16x8 w0 = *reinterpret_cast<const bf16x8*>(&sW[(n * 64 + lane) * 8]);
        bf16x8 w1 = *reinterpret_cast<const bf16x8*>(&sW[((16 + n) * 64 + lane) * 8]);
        f32x4 bi = *reinterpret_cast<const f32x4*>(&sBias[(n << 4) + (kH << 2)]);

        f32x4 cA = __builtin_amdgcn_mfma_f32_16x16x32_bf16(w0, A.a0, bi, 0, 0, 0);
        cA = __builtin_amdgcn_mfma_f32_16x16x32_bf16(w1, A.a1, cA, 0, 0, 0);
        f32x4 cB = __builtin_amdgcn_mfma_f32_16x16x32_bf16(w0, B.a0, bi, 0, 0, 0);
        cB = __builtin_amdgcn_mfma_f32_16x16x32_bf16(w1, B.a1, cB, 0, 0, 0);

        {   // tile A epilogue slice
            float e0 = __builtin_amdgcn_exp2f(cA[0]);
            float e1 = __builtin_amdgcn_exp2f(cA[1]);
            float e2 = __builtin_amdgcn_exp2f(cA[2]);
            float e3 = __builtin_amdgcn_exp2f(cA[3]);
            float bs = (e0 + e1) + (e2 + e3);
            dA += bs;
            float t0 = fmaf(e3, A.m[3], fmaf(e2, A.m[2], fmaf(e1, A.m[1], e0 * A.m[0])));
            float tp = fmaf(e3, A.pm[3], fmaf(e2, A.pm[2], fmaf(e1, A.pm[1], e0 * A.pm[0])));
            fA += (n < sbA) ? bs : ((n == sbA) ? t0 : 0.f);
            pA += (n == sbA1) ? tp : 0.f;
        }
        {   // tile B epilogue slice (independent chain)
            float e0 = __builtin_amdgcn_exp2f(cB[0]);
            float e1 = __builtin_amdgcn_exp2f(cB[1]);
            float e2 = __builtin_amdgcn_exp2f(cB[2]);
            float e3 = __builtin_amdgcn_exp2f(cB[3]);
            float bs = (e0 + e1) + (e2 + e3);
            dB += bs;
            float t0 = fmaf(e3, B.m[3], fmaf(e2, B.m[2], fmaf(e1, B.m[1], e0 * B.m[0])));
            float tp = fmaf(e3, B.pm[3], fmaf(e2, B.pm[2], fmaf(e1, B.pm[1], e0 * B.pm[0])));
            fB += (n < sbB) ? bs : ((n == sbB) ? t0 : 0.f);
            pB += (n == sbB1) ? tp : 0.f;
        }
    }

    dA += __shfl_xor(dA, 16, 64); fA += __shfl_xor(fA, 16, 64); pA += __shfl_xor(pA, 16, 64);
    dA += __shfl_xor(dA, 32, 64); fA += __shfl_xor(fA, 32, 64); pA += __shfl_xor(pA, 32, 64);
    dB += __shfl_xor(dB, 16, 64); fB += __shfl_xor(fB, 16, 64); pB += __shfl_xor(pB, 16, 64);
    dB += __shfl_xor(dB, 32, 64); fB += __shfl_xor(fB, 32, 64); pB += __shfl_xor(pB, 32, 64);

    if (kH == 0) {
        {
            float x0 = sBP[A.s], x1 = sBP[A.s + 1];
            float inv = 1.0f / dA;
            float slope = (pA * inv) / (x1 - x0);
            out[A.m0 + colb] = fmaf(slope, A.yv - x0, fA * inv);
            out[(size_t)NB * 65 + A.m0 + colb] = A.ldv + __logf(fabsf(slope));
        }
        {
            float x0 = sBP[B.s], x1 = sBP[B.s + 1];
            float inv = 1.0f / dB;
            float slope = (pB * inv) / (x1 - x0);
            out[B.m0 + colb] = fmaf(slope, B.yv - x0, fB * inv);
            out[(size_t)NB * 65 + B.m0 + colb] = B.ldv + __logf(fabsf(slope));
        }
    }
}

#define LOADT(wt, v0, v1, v2, v3, yv, ldv)                                     \
    {                                                                          \
        const float* xr = x + (size_t)(((wt) << 4) + colb) * 64 + (kH << 3);   \
        v0 = *reinterpret_cast<const f32x4*>(xr);                              \
        v1 = *reinterpret_cast<const f32x4*>(xr + 4);                          \
        v2 = *reinterpret_cast<const f32x4*>(xr + 32);                         \
        v3 = *reinterpret_cast<const f32x4*>(xr + 36);                         \
        yv  = y[((wt) << 4) + colb];                                           \
        ldv = logdet[((wt) << 4) + colb];                                      \
    }

__global__ __launch_bounds__(512, 2) void interp1d_kernel(
    const float* __restrict__ y, const float* __restrict__ x,
    const float* __restrict__ W, const float* __restrict__ bias,
    const float* __restrict__ logdet, const float* __restrict__ bp,
    float* __restrict__ out)
{
    __shared__ unsigned short sW[2 * 16 * 64 * 8];   // 32KB, [kb][n][lane][i] frag layout
    __shared__ float sBP[256];
    __shared__ float sBias[256];                     // pre-scaled by log2e

    const int t = threadIdx.x;

    // --- once per block: bp, bias*log2e, W*log2e packed into MFMA fragment layout ---
    if (t < 256) {
        sBP[t]   = bp[t];
        sBias[t] = bias[t] * LOG2E;
    }
    {
        const int col = t & 255;
        const int k0  = (t >> 8) << 5;
        const int lane16lo = col & 15;
        const int n = col >> 4;
        for (int kk = 0; kk < 32; ++kk) {
            int k = k0 + kk;
            float wv = W[k * 256 + col] * LOG2E;      // coalesced within each 256-thread half
            int lane16 = ((k >> 3) & 3) * 16 + lane16lo;
            int kb = k >> 5, i = k & 7;
            sW[((kb * 16 + n) * 64 + lane16) * 8 + i] = f2b(wv);
        }
    }
    __syncthreads();

    const int lane = t & 63;
    const int colb = lane & 15;     // this lane's x-row within each tile (C column)
    const int kH   = lane >> 4;     // 0..3
    const int wid  = (blockIdx.x << 3) | (t >> 6);   // 0..4095

    // --- preload first pair (tiles 2*wid, 2*wid+1) ---
    f32x4 A0, A1, A2, A3, B0, B1, B2, B3;
    float yA, lA, yB, lB;
    LOADT(2 * wid,     A0, A1, A2, A3, yA, lA);
    LOADT(2 * wid + 1, B0, B1, B2, B3, yB, lB);

    for (int p = wid; p < NPAIRS; p += NWAVES) {
        const int pn = p + NWAVES;

        // --- stage1 both tiles (consumes the raw x regs: store + pack + search + masks) ---
        TState sA = stage1(2 * p,     A0, A1, A2, A3, yA, lA, colb, kH, sBP, out);
        TState sB = stage1(2 * p + 1, B0, B1, B2, B3, yB, lB, colb, kH, sBP, out);

        // --- prefetch next pair into the now-free x regs; latency hidden by the n-loop ---
        if (pn < NPAIRS) {
            LOADT(2 * pn,     A0, A1, A2, A3, yA, lA);
            LOADT(2 * pn + 1, B0, B1, B2, B3, yB, lB);
        }

        // fence: keep sW ds_reads inside the loop (r3 LICM lesson) + keep prefetch issued
        asm volatile("" ::: "memory");

        // --- shared-W n-loop for the pair + reduce + stores ---
        stage2_pair(sA, sB, lane, colb, kH, sW, sBP, sBias, out);
    }
}

extern "C" void kernel_launch(void* const* d_in, const int* in_sizes, int n_in,
                              void* d_out, int out_size, void* d_ws, size_t ws_size,
                              hipStream_t stream) {
    (void)in_sizes; (void)n_in; (void)out_size; (void)d_ws; (void)ws_size;
    const float* y      = (const float*)d_in[0];
    const float* x      = (const float*)d_in[1];
    const float* W      = (const float*)d_in[2];
    const float* b      = (const float*)d_in[3];
    const float* logdet = (const float*)d_in[4];
    const float* bp     = (const float*)d_in[5];
    float* out = (float*)d_out;
    // 512 blocks x 512 thr = 4096 waves; 16384 pairs -> exactly 4 pair-iters/wave.
    // 2 blocks/CU resident (regs ~110 -> 4 waves/SIMD, same as every measured config).
    interp1d_kernel<<<dim3(512), dim3(512), 0, stream>>>(y, x, W, b, logdet, bp, out);
}